// Round 1
// baseline (665.368 us; speedup 1.0000x reference)
//
#include <hip/hip_runtime.h>

#define NN 8
#define HH 12
#define DH 64
#define LV 1568
#define LA 512
#define NCV 392
#define NCA 256
#define SCALE 0.125f

#define OUT_STRIDE (LV + LA + 2 * HH * DH + LV + LA)   // 5696
#define OFF_PROB_V 0
#define OFF_PROB_A (LV)                                 // 1568
#define OFF_VCLS   (LV + LA)                            // 2080
#define OFF_ACLS   (LV + LA + HH * DH)                  // 2848
#define OFF_PR_AV  (LV + LA + 2 * HH * DH)              // 3616
#define OFF_PR_VA  (LV + LA + 2 * HH * DH + LV)         // 5184

// workspace layout (float offsets)
#define WS_RV      0                                    // N*H*LV = 150528
#define WS_RA      (NN * HH * LV)                       // N*H*LA = 49152
#define WS_WAV     (WS_RA + NN * HH * LA)               // N*NCV
#define WS_WVA     (WS_WAV + NN * NCV)                  // N*NCA
#define WS_INV_SAV (WS_WVA + NN * NCA)                  // N
#define WS_INV_SVA (WS_INV_SAV + NN)                    // N

#define CHA 8   // row-chunks for av rowsum: 256/8 = 32 rows/chunk
#define CHV 8   // row-chunks for va rowsum: 392/8 = 49 rows/chunk

// ---------------------------------------------------------------------------
// prep: gather per-token weights w_av[l]=n_attn_av[n, idx_v[l]] (l<NCV) and
// w_va, compute reciprocal sums. Grid: N blocks x 512 threads.
// ---------------------------------------------------------------------------
__global__ void prep_kernel(const float* __restrict__ n_av,
                            const float* __restrict__ n_va,
                            const int* __restrict__ av_ids,
                            const int* __restrict__ va_ids,
                            float* __restrict__ ws) {
    int n = blockIdx.x;
    int t = threadIdx.x;           // 512 threads = 8 waves
    int wave = t >> 6;

    float wv = 0.f, wa = 0.f;
    if (t < NCV) {
        wv = n_av[n * LV + av_ids[n * LV + t]];
        ws[WS_WAV + n * NCV + t] = wv;
    }
    if (t < NCA) {
        wa = n_va[n * LA + va_ids[n * LA + t]];
        ws[WS_WVA + n * NCA + t] = wa;
    }
    float vs = wv, as = wa;
    for (int m = 32; m; m >>= 1) { vs += __shfl_xor(vs, m); as += __shfl_xor(as, m); }
    __shared__ float sv[8], sa[8];
    if ((t & 63) == 0) { sv[wave] = vs; sa[wave] = as; }
    __syncthreads();
    if (t == 0) {
        float S0 = 0.f, S1 = 0.f;
        #pragma unroll
        for (int i = 0; i < 8; ++i) { S0 += sv[i]; S1 += sa[i]; }
        ws[WS_INV_SAV + n] = 1.f / S0;
        ws[WS_INV_SVA + n] = 1.f / S1;
    }
}

// ---------------------------------------------------------------------------
// rowsum: Rv[n,h,c] = sum_a av[n,h,idx_a[a],c] * w_va[a]   (c in [0,LV))
//         Ra[n,h,c] = sum_v va[n,h,idx_v[v],c] * w_av[v]   (c in [0,LA))
// Full coalesced rows; chunked over selected rows, atomicAdd partials.
// Grid: N*H*CHA + N*H*CHV blocks x 256 threads.
// ---------------------------------------------------------------------------
__global__ __launch_bounds__(256) void rowsum_kernel(
        const float* __restrict__ av,   // (N,H,LA,LV)
        const float* __restrict__ va,   // (N,H,LV,LA)
        const int* __restrict__ av_ids,
        const int* __restrict__ va_ids,
        float* __restrict__ ws) {
    int b = blockIdx.x;
    int t = threadIdx.x;
    if (b < NN * HH * CHA) {
        int chunk = b % CHA;
        int nh    = b / CHA;
        int n     = nh / HH;
        const int rows = NCA / CHA;        // 32
        float4 acc0 = {0.f, 0.f, 0.f, 0.f};
        float4 acc1 = {0.f, 0.f, 0.f, 0.f};
        const int c0 = t;                  // float4 column
        const int c1 = t + 256;
        const bool has1 = (c1 < LV / 4);   // LV/4 = 392
        for (int r = 0; r < rows; ++r) {
            int a = chunk * rows + r;
            int ridx = va_ids[n * LA + a];
            float w  = ws[WS_WVA + n * NCA + a];
            const float4* row = (const float4*)(av + ((size_t)nh * LA + ridx) * LV);
            float4 x0 = row[c0];
            acc0.x += x0.x * w; acc0.y += x0.y * w; acc0.z += x0.z * w; acc0.w += x0.w * w;
            if (has1) {
                float4 x1 = row[c1];
                acc1.x += x1.x * w; acc1.y += x1.y * w; acc1.z += x1.z * w; acc1.w += x1.w * w;
            }
        }
        float* out = ws + WS_RV + (size_t)nh * LV;
        atomicAdd(&out[c0 * 4 + 0], acc0.x);
        atomicAdd(&out[c0 * 4 + 1], acc0.y);
        atomicAdd(&out[c0 * 4 + 2], acc0.z);
        atomicAdd(&out[c0 * 4 + 3], acc0.w);
        if (has1) {
            atomicAdd(&out[c1 * 4 + 0], acc1.x);
            atomicAdd(&out[c1 * 4 + 1], acc1.y);
            atomicAdd(&out[c1 * 4 + 2], acc1.z);
            atomicAdd(&out[c1 * 4 + 3], acc1.w);
        }
    } else {
        int b2    = b - NN * HH * CHA;
        int chunk = b2 % CHV;
        int nh    = b2 / CHV;
        int n     = nh / HH;
        const int rows = NCV / CHV;        // 49
        float2 acc = {0.f, 0.f};
        const int c = t;                   // float2 column, LA/2 = 256 exactly
        for (int r = 0; r < rows; ++r) {
            int v = chunk * rows + r;
            int ridx = av_ids[n * LV + v];
            float w  = ws[WS_WAV + n * NCV + v];
            const float2* row = (const float2*)(va + ((size_t)nh * LV + ridx) * LA);
            float2 x = row[c];
            acc.x += x.x * w; acc.y += x.y * w;
        }
        float* out = ws + WS_RA + (size_t)nh * LA;
        atomicAdd(&out[c * 2 + 0], acc.x);
        atomicAdd(&out[c * 2 + 1], acc.y);
    }
}

// ---------------------------------------------------------------------------
// cls: pos_v_cls[n,h,d] = (sum_l pos_v_q[n,h,idx_v[l],d]*w_av[l]) * invS_av
//      pos_a_cls analogous. Grid: 2*N*H blocks x 256 threads (4 waves).
// ---------------------------------------------------------------------------
__global__ __launch_bounds__(256) void cls_kernel(
        const float* __restrict__ pvq,
        const float* __restrict__ paq,
        const int* __restrict__ av_ids,
        const int* __restrict__ va_ids,
        const float* __restrict__ ws,
        float* __restrict__ out) {
    int b = blockIdx.x;
    int t = threadIdx.x;
    int wave = t >> 6, lane = t & 63;
    __shared__ float red[4][DH];
    if (b < NN * HH) {
        int n = b / HH, h = b % HH;
        float acc = 0.f;
        for (int l = wave; l < NCV; l += 4) {
            int ridx = av_ids[n * LV + l];
            float w  = ws[WS_WAV + n * NCV + l];
            acc += pvq[((size_t)b * LV + ridx) * DH + lane] * w;
        }
        red[wave][lane] = acc;
        __syncthreads();
        if (wave == 0) {
            float s = red[0][lane] + red[1][lane] + red[2][lane] + red[3][lane];
            out[(size_t)n * OUT_STRIDE + OFF_VCLS + h * DH + lane] = s * ws[WS_INV_SAV + n];
        }
    } else {
        int b2 = b - NN * HH;
        int n = b2 / HH, h = b2 % HH;
        float acc = 0.f;
        for (int l = wave; l < NCA; l += 4) {
            int ridx = va_ids[n * LA + l];
            float w  = ws[WS_WVA + n * NCA + l];
            acc += paq[((size_t)b2 * LA + ridx) * DH + lane] * w;
        }
        red[wave][lane] = acc;
        __syncthreads();
        if (wave == 0) {
            float s = red[0][lane] + red[1][lane] + red[2][lane] + red[3][lane];
            out[(size_t)n * OUT_STRIDE + OFF_ACLS + h * DH + lane] = s * ws[WS_INV_SVA + n];
        }
    }
}

// ---------------------------------------------------------------------------
// prob: one wave per (n, selected-token). 12 head dot-products of length 64
// (lane = d), butterfly reduce, sigmoid(spu - pos), mean over heads,
// scatter to out[n, ids[l]].
// ---------------------------------------------------------------------------
__global__ __launch_bounds__(256) void prob_kernel(
        const float* __restrict__ pvk,
        const float* __restrict__ pak,
        const float* __restrict__ spu_a,   // (N,H,DH)
        const float* __restrict__ spu_v,
        const int* __restrict__ av_ids,
        const int* __restrict__ va_ids,
        const float* __restrict__ ws,
        float* __restrict__ out) {
    int W = blockIdx.x * 4 + (threadIdx.x >> 6);
    int lane = threadIdx.x & 63;
    if (W < NN * NCV) {
        int n = W / NCV, l = W % NCV;
        int col = av_ids[n * LV + l];
        float invS = ws[WS_INV_SVA + n];
        float psum = 0.f;
        #pragma unroll
        for (int h = 0; h < HH; ++h) {
            int nh = n * HH + h;
            float prod = pvk[((size_t)nh * LV + col) * DH + lane] * spu_a[nh * DH + lane];
            for (int m = 32; m; m >>= 1) prod += __shfl_xor(prod, m);
            float spu = prod * SCALE;
            float pos = ws[WS_RV + (size_t)nh * LV + col] * invS;
            psum += 1.f / (1.f + __expf(pos - spu));
        }
        if (lane == 0)
            out[(size_t)n * OUT_STRIDE + OFF_PROB_V + col] = psum * (1.f / HH);
    } else if (W < NN * NCV + NN * NCA) {
        int W2 = W - NN * NCV;
        int n = W2 / NCA, l = W2 % NCA;
        int col = va_ids[n * LA + l];
        float invS = ws[WS_INV_SAV + n];
        float psum = 0.f;
        #pragma unroll
        for (int h = 0; h < HH; ++h) {
            int nh = n * HH + h;
            float prod = pak[((size_t)nh * LA + col) * DH + lane] * spu_v[nh * DH + lane];
            for (int m = 32; m; m >>= 1) prod += __shfl_xor(prod, m);
            float spu = prod * SCALE;
            float pos = ws[WS_RA + (size_t)nh * LA + col] * invS;
            psum += 1.f / (1.f + __expf(pos - spu));
        }
        if (lane == 0)
            out[(size_t)n * OUT_STRIDE + OFF_PROB_A + col] = psum * (1.f / HH);
    }
}

// ---------------------------------------------------------------------------
// prune: prune_n_av = (u_v < prob_v_full) ? 0 : n_attn_av ; same for a.
// ---------------------------------------------------------------------------
__global__ __launch_bounds__(256) void prune_kernel(
        const float* __restrict__ n_av,
        const float* __restrict__ n_va,
        const float* __restrict__ u_v,
        const float* __restrict__ u_a,
        float* __restrict__ out) {
    int t = blockIdx.x * 256 + threadIdx.x;
    const int total = NN * (LV + LA);
    if (t >= total) return;
    int n = t / (LV + LA);
    int j = t % (LV + LA);
    if (j < LV) {
        float prob = out[(size_t)n * OUT_STRIDE + OFF_PROB_V + j];
        float uv   = u_v[n * LV + j];
        out[(size_t)n * OUT_STRIDE + OFF_PR_AV + j] = (uv < prob) ? 0.f : n_av[n * LV + j];
    } else {
        int j2 = j - LV;
        float prob = out[(size_t)n * OUT_STRIDE + OFF_PROB_A + j2];
        float ua   = u_a[n * LA + j2];
        out[(size_t)n * OUT_STRIDE + OFF_PR_VA + j2] = (ua < prob) ? 0.f : n_va[n * LA + j2];
    }
}

extern "C" void kernel_launch(void* const* d_in, const int* in_sizes, int n_in,
                              void* d_out, int out_size, void* d_ws, size_t ws_size,
                              hipStream_t stream) {
    const float* pvq   = (const float*)d_in[0];
    const float* pvk   = (const float*)d_in[1];
    const float* paq   = (const float*)d_in[2];
    const float* pak   = (const float*)d_in[3];
    const float* av    = (const float*)d_in[4];
    const float* va    = (const float*)d_in[5];
    const float* n_av  = (const float*)d_in[6];
    const float* n_va  = (const float*)d_in[7];
    const float* spu_a = (const float*)d_in[8];
    const float* spu_v = (const float*)d_in[9];
    const float* u_v   = (const float*)d_in[10];
    const float* u_a   = (const float*)d_in[11];
    const int* av_ids  = (const int*)d_in[12];
    const int* va_ids  = (const int*)d_in[13];
    float* out = (float*)d_out;
    float* ws  = (float*)d_ws;

    // zero output (covers unselected prob slots) and rowsum accumulators
    hipMemsetAsync(d_out, 0, (size_t)out_size * sizeof(float), stream);
    hipMemsetAsync(d_ws, 0, (size_t)(NN * HH * LV + NN * HH * LA) * sizeof(float), stream);

    prep_kernel<<<NN, 512, 0, stream>>>(n_av, n_va, av_ids, va_ids, ws);
    rowsum_kernel<<<NN * HH * (CHA + CHV), 256, 0, stream>>>(av, va, av_ids, va_ids, ws);
    cls_kernel<<<2 * NN * HH, 256, 0, stream>>>(pvq, paq, av_ids, va_ids, ws, out);
    int waves = NN * NCV + NN * NCA;
    prob_kernel<<<(waves + 3) / 4, 256, 0, stream>>>(pvk, pak, spu_a, spu_v,
                                                     av_ids, va_ids, ws, out);
    prune_kernel<<<(NN * (LV + LA) + 255) / 256, 256, 0, stream>>>(n_av, n_va, u_v, u_a, out);
}

// Round 2
// 645.224 us; speedup vs baseline: 1.0312x; 1.0312x over previous
//
#include <hip/hip_runtime.h>

#define NN 8
#define HH 12
#define DH 64
#define LV 1568
#define LA 512
#define NCV 392
#define NCA 256
#define SCALE 0.125f

#define OUT_STRIDE (LV + LA + 2 * HH * DH + LV + LA)   // 5696
#define OFF_PROB_V 0
#define OFF_PROB_A (LV)                                 // 1568
#define OFF_VCLS   (LV + LA)                            // 2080
#define OFF_ACLS   (LV + LA + HH * DH)                  // 2848
#define OFF_PR_AV  (LV + LA + 2 * HH * DH)              // 3616
#define OFF_PR_VA  (LV + LA + 2 * HH * DH + LV)         // 5184

// workspace layout (float offsets)
#define WS_RV      0                                    // N*H*LV = 150528
#define WS_RA      (NN * HH * LV)                       // N*H*LA = 49152
#define WS_INV_SAV (WS_RA + NN * HH * LA)               // N
#define WS_INV_SVA (WS_INV_SAV + NN)                    // N

#define CHA 8   // row-chunks for av rowsum: 256/8 = 32 rows/chunk
#define CHV 8   // row-chunks for va rowsum: 392/8 = 49 rows/chunk

// ---------------------------------------------------------------------------
// init: zero RV/RA accumulators (float4 stores) + blocks 0..NN-1 also compute
// 1/sum(gathered n_attn) for both modalities. Grid: 256 blocks x 256 threads.
// ---------------------------------------------------------------------------
__global__ __launch_bounds__(256) void init_kernel(
        const float* __restrict__ n_av,
        const float* __restrict__ n_va,
        const int* __restrict__ av_ids,
        const int* __restrict__ va_ids,
        float* __restrict__ ws) {
    int t = threadIdx.x;
    int idx = blockIdx.x * 256 + t;
    const int total4 = (NN * HH * LV + NN * HH * LA) / 4;   // 49920
    if (idx < total4) ((float4*)ws)[idx] = make_float4(0.f, 0.f, 0.f, 0.f);

    if (blockIdx.x < NN) {
        int n = blockIdx.x;
        float vs = 0.f, as = 0.f;
        for (int l = t; l < NCV; l += 256) vs += n_av[n * LV + av_ids[n * LV + l]];
        if (t < NCA) as = n_va[n * LA + va_ids[n * LA + t]];
        for (int m = 32; m; m >>= 1) { vs += __shfl_xor(vs, m); as += __shfl_xor(as, m); }
        __shared__ float sv[4], sa[4];
        int wave = t >> 6;
        if ((t & 63) == 0) { sv[wave] = vs; sa[wave] = as; }
        __syncthreads();
        if (t == 0) {
            float S0 = sv[0] + sv[1] + sv[2] + sv[3];
            float S1 = sa[0] + sa[1] + sa[2] + sa[3];
            ws[WS_INV_SAV + n] = 1.f / S0;
            ws[WS_INV_SVA + n] = 1.f / S1;
        }
    }
}

// ---------------------------------------------------------------------------
// rowsum: Rv[n,h,c] = sum_a av[n,h,idx_a[a],c] * n_va[n,idx_a[a]]
//         Ra[n,h,c] = sum_v va[n,h,idx_v[v],c] * n_av[n,idx_v[v]]
// Full coalesced rows; chunked over selected rows, atomicAdd partials.
// ---------------------------------------------------------------------------
__global__ __launch_bounds__(256) void rowsum_kernel(
        const float* __restrict__ av,   // (N,H,LA,LV)
        const float* __restrict__ va,   // (N,H,LV,LA)
        const int* __restrict__ av_ids,
        const int* __restrict__ va_ids,
        const float* __restrict__ n_av,
        const float* __restrict__ n_va,
        float* __restrict__ ws) {
    int b = blockIdx.x;
    int t = threadIdx.x;
    if (b < NN * HH * CHA) {
        int chunk = b % CHA;
        int nh    = b / CHA;
        int n     = nh / HH;
        const int rows = NCA / CHA;        // 32
        float4 acc0 = {0.f, 0.f, 0.f, 0.f};
        float4 acc1 = {0.f, 0.f, 0.f, 0.f};
        const int c0 = t;                  // float4 column
        const int c1 = t + 256;
        const bool has1 = (c1 < LV / 4);   // LV/4 = 392
        for (int r = 0; r < rows; ++r) {
            int a = chunk * rows + r;
            int ridx = va_ids[n * LA + a];
            float w  = n_va[n * LA + ridx];
            const float4* row = (const float4*)(av + ((size_t)nh * LA + ridx) * LV);
            float4 x0 = row[c0];
            acc0.x += x0.x * w; acc0.y += x0.y * w; acc0.z += x0.z * w; acc0.w += x0.w * w;
            if (has1) {
                float4 x1 = row[c1];
                acc1.x += x1.x * w; acc1.y += x1.y * w; acc1.z += x1.z * w; acc1.w += x1.w * w;
            }
        }
        float* out = ws + WS_RV + (size_t)nh * LV;
        atomicAdd(&out[c0 * 4 + 0], acc0.x);
        atomicAdd(&out[c0 * 4 + 1], acc0.y);
        atomicAdd(&out[c0 * 4 + 2], acc0.z);
        atomicAdd(&out[c0 * 4 + 3], acc0.w);
        if (has1) {
            atomicAdd(&out[c1 * 4 + 0], acc1.x);
            atomicAdd(&out[c1 * 4 + 1], acc1.y);
            atomicAdd(&out[c1 * 4 + 2], acc1.z);
            atomicAdd(&out[c1 * 4 + 3], acc1.w);
        }
    } else {
        int b2    = b - NN * HH * CHA;
        int chunk = b2 % CHV;
        int nh    = b2 / CHV;
        int n     = nh / HH;
        const int rows = NCV / CHV;        // 49
        float2 acc = {0.f, 0.f};
        const int c = t;                   // float2 column, LA/2 = 256 exactly
        for (int r = 0; r < rows; ++r) {
            int v = chunk * rows + r;
            int ridx = av_ids[n * LV + v];
            float w  = n_av[n * LV + ridx];
            const float2* row = (const float2*)(va + ((size_t)nh * LV + ridx) * LA);
            float2 x = row[c];
            acc.x += x.x * w; acc.y += x.y * w;
        }
        float* out = ws + WS_RA + (size_t)nh * LA;
        atomicAdd(&out[c * 2 + 0], acc.x);
        atomicAdd(&out[c * 2 + 1], acc.y);
    }
}

// ---------------------------------------------------------------------------
// cls: self-contained — gathers q rows + weights, block-reduces weight sum,
// writes normalized class token. Grid: 2*N*H blocks x 256 threads.
// ---------------------------------------------------------------------------
__global__ __launch_bounds__(256) void cls_kernel(
        const float* __restrict__ pvq,
        const float* __restrict__ paq,
        const int* __restrict__ av_ids,
        const int* __restrict__ va_ids,
        const float* __restrict__ n_av,
        const float* __restrict__ n_va,
        float* __restrict__ out) {
    int b = blockIdx.x;
    int t = threadIdx.x;
    int wave = t >> 6, lane = t & 63;
    __shared__ float red[4][DH];
    __shared__ float wred[4];
    if (b < NN * HH) {
        int n = b / HH, h = b % HH;
        float acc = 0.f, wsum = 0.f;
        for (int l = wave; l < NCV; l += 4) {
            int ridx = av_ids[n * LV + l];
            float w  = n_av[n * LV + ridx];
            acc  += pvq[((size_t)b * LV + ridx) * DH + lane] * w;
            wsum += w;
        }
        red[wave][lane] = acc;
        if (lane == 0) wred[wave] = wsum;
        __syncthreads();
        if (wave == 0) {
            float s = red[0][lane] + red[1][lane] + red[2][lane] + red[3][lane];
            float W = wred[0] + wred[1] + wred[2] + wred[3];
            out[(size_t)n * OUT_STRIDE + OFF_VCLS + h * DH + lane] = s / W;
        }
    } else {
        int b2 = b - NN * HH;
        int n = b2 / HH, h = b2 % HH;
        float acc = 0.f, wsum = 0.f;
        for (int l = wave; l < NCA; l += 4) {
            int ridx = va_ids[n * LA + l];
            float w  = n_va[n * LA + ridx];
            acc  += paq[((size_t)b2 * LA + ridx) * DH + lane] * w;
            wsum += w;
        }
        red[wave][lane] = acc;
        if (lane == 0) wred[wave] = wsum;
        __syncthreads();
        if (wave == 0) {
            float s = red[0][lane] + red[1][lane] + red[2][lane] + red[3][lane];
            float W = wred[0] + wred[1] + wred[2] + wred[3];
            out[(size_t)n * OUT_STRIDE + OFF_ACLS + h * DH + lane] = s / W;
        }
    }
}

// ---------------------------------------------------------------------------
// prob+scatter+prune fused: one wave per (n, token-rank l) covering ALL L
// tokens. l < NC: 12 head-dots (lane=d) via butterfly + sigmoid mean;
// l >= NC: prob = 0. Lane 0 writes scattered prob AND prune at that column.
// Grid: N*(LV+LA)/4 blocks x 256 threads.
// ---------------------------------------------------------------------------
__global__ __launch_bounds__(256) void prob_kernel(
        const float* __restrict__ pvk,
        const float* __restrict__ pak,
        const float* __restrict__ spu_a,   // (N,H,DH)
        const float* __restrict__ spu_v,
        const int* __restrict__ av_ids,
        const int* __restrict__ va_ids,
        const float* __restrict__ n_av,
        const float* __restrict__ n_va,
        const float* __restrict__ u_v,
        const float* __restrict__ u_a,
        const float* __restrict__ ws,
        float* __restrict__ out) {
    int W = blockIdx.x * 4 + (threadIdx.x >> 6);
    int lane = threadIdx.x & 63;
    const int TV = NN * LV;
    if (W < TV) {
        int n = W / LV, l = W % LV;
        int col = av_ids[n * LV + l];
        float p = 0.f;
        if (l < NCV) {
            float invS = ws[WS_INV_SVA + n];
            float psum = 0.f;
            #pragma unroll
            for (int h = 0; h < HH; ++h) {
                int nh = n * HH + h;
                float prod = pvk[((size_t)nh * LV + col) * DH + lane] * spu_a[nh * DH + lane];
                for (int m = 32; m; m >>= 1) prod += __shfl_xor(prod, m);
                float spu = prod * SCALE;
                float pos = ws[WS_RV + (size_t)nh * LV + col] * invS;
                psum += 1.f / (1.f + __expf(pos - spu));
            }
            p = psum * (1.f / HH);
        }
        if (lane == 0) {
            out[(size_t)n * OUT_STRIDE + OFF_PROB_V + col] = p;
            float uv = u_v[n * LV + col];
            out[(size_t)n * OUT_STRIDE + OFF_PR_AV + col] =
                (uv < p) ? 0.f : n_av[n * LV + col];
        }
    } else {
        int W2 = W - TV;
        int n = W2 / LA, l = W2 % LA;
        int col = va_ids[n * LA + l];
        float p = 0.f;
        if (l < NCA) {
            float invS = ws[WS_INV_SAV + n];
            float psum = 0.f;
            #pragma unroll
            for (int h = 0; h < HH; ++h) {
                int nh = n * HH + h;
                float prod = pak[((size_t)nh * LA + col) * DH + lane] * spu_v[nh * DH + lane];
                for (int m = 32; m; m >>= 1) prod += __shfl_xor(prod, m);
                float spu = prod * SCALE;
                float pos = ws[WS_RA + (size_t)nh * LA + col] * invS;
                psum += 1.f / (1.f + __expf(pos - spu));
            }
            p = psum * (1.f / HH);
        }
        if (lane == 0) {
            out[(size_t)n * OUT_STRIDE + OFF_PROB_A + col] = p;
            float ua = u_a[n * LA + col];
            out[(size_t)n * OUT_STRIDE + OFF_PR_VA + col] =
                (ua < p) ? 0.f : n_va[n * LA + col];
        }
    }
}

extern "C" void kernel_launch(void* const* d_in, const int* in_sizes, int n_in,
                              void* d_out, int out_size, void* d_ws, size_t ws_size,
                              hipStream_t stream) {
    const float* pvq   = (const float*)d_in[0];
    const float* pvk   = (const float*)d_in[1];
    const float* paq   = (const float*)d_in[2];
    const float* pak   = (const float*)d_in[3];
    const float* av    = (const float*)d_in[4];
    const float* va    = (const float*)d_in[5];
    const float* n_av  = (const float*)d_in[6];
    const float* n_va  = (const float*)d_in[7];
    const float* spu_a = (const float*)d_in[8];
    const float* spu_v = (const float*)d_in[9];
    const float* u_v   = (const float*)d_in[10];
    const float* u_a   = (const float*)d_in[11];
    const int* av_ids  = (const int*)d_in[12];
    const int* va_ids  = (const int*)d_in[13];
    float* out = (float*)d_out;
    float* ws  = (float*)d_ws;

    init_kernel<<<256, 256, 0, stream>>>(n_av, n_va, av_ids, va_ids, ws);
    rowsum_kernel<<<NN * HH * (CHA + CHV), 256, 0, stream>>>(av, va, av_ids, va_ids,
                                                             n_av, n_va, ws);
    cls_kernel<<<2 * NN * HH, 256, 0, stream>>>(pvq, paq, av_ids, va_ids,
                                                n_av, n_va, out);
    prob_kernel<<<NN * (LV + LA) / 4, 256, 0, stream>>>(pvk, pak, spu_a, spu_v,
                                                        av_ids, va_ids, n_av, n_va,
                                                        u_v, u_a, ws, out);
}